// Round 7
// baseline (8688.763 us; speedup 1.0000x reference)
//
#include <hip/hip_runtime.h>
#include <hip/hip_bf16.h>

#define N_NODES 50000
#define N_EDGES 800000
#define DIM 128
#define BN_EPS 1e-5f

typedef __attribute__((ext_vector_type(8))) short short8;
typedef __attribute__((ext_vector_type(4))) float float4v;

__device__ __forceinline__ float bf16_bits_to_f32(unsigned short u) {
    union { unsigned int i; float f; } c;
    c.i = ((unsigned int)u) << 16;
    return c.f;
}

__device__ __forceinline__ unsigned short f32_to_bf16_bits(float f) {
    union { float f; unsigned int i; } c;
    c.f = f;
    unsigned int lsb = (c.i >> 16) & 1u;
    c.i += 0x7FFFu + lsb;   // RNE
    return (unsigned short)(c.i >> 16);
}

__device__ __forceinline__ bool badf(float f) {
    union { float f; unsigned int u; } c;
    c.f = f;
    return (c.u & 0x7F800000u) == 0x7F800000u;
}

// ---------------- dtype sniff: is x f32 or bf16? ----------------
// True bf16 N(0,1): every u16 has exponent byte in [96,159] (~512/512).
// f32-as-u16: even u16s are uniform mantissa bits -> only ~25% plausible (~320/512).
__global__ __launch_bounds__(256) void sniff(const unsigned short* __restrict__ xu,
                                             float* __restrict__ mode) {
    __shared__ int cnt;
    if (threadIdx.x == 0) cnt = 0;
    __syncthreads();
    int ok = 0;
    for (int i = threadIdx.x; i < 512; i += 256) {
        unsigned e = (xu[i] >> 7) & 0xFFu;
        if (e >= 96u && e <= 159u) ok++;
    }
    atomicAdd(&cnt, ok);
    __syncthreads();
    if (threadIdx.x == 0) mode[0] = (cnt >= 480) ? 0.0f : 1.0f;  // 0=bf16, 1=f32
}

// ---------------- zero-init (hipMemsetAsync in kernel_launch kills the stream) ----------------
__global__ __launch_bounds__(256) void zero_buf(float* __restrict__ p, int n) {
    int i = blockIdx.x * blockDim.x + threadIdx.x;
    if (i < n) p[i] = 0.0f;
}

// ---------------- canonicalize params: W -> bf16 Wc, b/gamma/beta -> f32 pf32 ----------------
__global__ __launch_bounds__(256) void convert_params(
    const void* __restrict__ W, const void* __restrict__ b,
    const void* __restrict__ g, const void* __restrict__ be,
    const float* __restrict__ mode,
    unsigned short* __restrict__ Wc, float* __restrict__ pf32) {
    const bool mf32 = mode[0] > 0.5f;
    int i = blockIdx.x * blockDim.x + threadIdx.x;
    const int NW = 3 * DIM * DIM;  // 49152
    if (i < NW) {
        Wc[i] = mf32 ? f32_to_bf16_bits(((const float*)W)[i])
                     : ((const unsigned short*)W)[i];
    } else if (i < NW + 3 * 3 * DIM) {
        int p = i - NW;              // 0..1151
        int which = p / 384;         // 0=b 1=gamma 2=beta
        int r = p - which * 384;     // l*128 + c
        const void* srcp = (which == 0) ? b : (which == 1) ? g : be;
        float v = mf32 ? ((const float*)srcp)[r]
                       : bf16_bits_to_f32(((const unsigned short*)srcp)[r]);
        pf32[which * 384 + r] = v;
    }
}

// ---------------- degree / dinv (edge_index proven int32, in-range in round 6) ----------------
__global__ __launch_bounds__(256) void deg_count(const int* __restrict__ dst,
                                                 float* __restrict__ deg) {
    int e = blockIdx.x * blockDim.x + threadIdx.x;
    if (e < N_EDGES) atomicAdd(&deg[dst[e]], 1.0f);
}

__global__ __launch_bounds__(256) void make_dinv(float* __restrict__ deg) {
    int v = blockIdx.x * blockDim.x + threadIdx.x;
    if (v < N_NODES) deg[v] = rsqrtf(deg[v] + 1.0f);  // +1 self-loop
}

// ---------------- GEMM (MFMA, verified vs VALU in r5): msg = dinv[row]*(h@W) ----------------
// use_x: layer 0 reads hsrc as x (dtype per mode). Layers 1/2 read hsrc as bf16
// hidden which ALIASES A (d_out): register-preload + __syncthreads (drains vmcnt)
// before any store; each block touches only its own 16-row stripe.
__global__ __launch_bounds__(256) void gemm_scale(
    const void* hsrc, int use_x,
    const unsigned short* __restrict__ Wl,  // [128,128] bf16 canonical
    const float* __restrict__ dinv,
    const float* __restrict__ mode,
    unsigned short* A,                      // [N,128] bf16 messages (may alias hsrc)
    float* __restrict__ B) {                // [N,128] fp32 accumulator
    const int wave = threadIdx.x >> 6;
    const int lane = threadIdx.x & 63;
    const int quad = lane >> 4;
    const int nidx = lane & 15;
    const int row0 = blockIdx.x * 16;
    const bool srcf32 = use_x && (mode[0] > 0.5f);

    short8 afrag[4];
    if (srcf32) {
        const float* xf = (const float*)hsrc;
        #pragma unroll
        for (int kk = 0; kk < 4; ++kk) {
            #pragma unroll
            for (int j = 0; j < 8; ++j)
                afrag[kk][j] = (short)f32_to_bf16_bits(
                    xf[(size_t)(row0 + nidx) * DIM + kk * 32 + quad * 8 + j]);
        }
    } else {
        const unsigned short* hu = (const unsigned short*)hsrc;
        #pragma unroll
        for (int kk = 0; kk < 4; ++kk)
            afrag[kk] = *(const short8*)(hu + (size_t)(row0 + nidx) * DIM + kk * 32 + quad * 8);
    }

    short8 bfrag[2][4];
    #pragma unroll
    for (int half = 0; half < 2; ++half) {
        int col0 = wave * 32 + half * 16;
        #pragma unroll
        for (int kk = 0; kk < 4; ++kk) {
            #pragma unroll
            for (int j = 0; j < 8; ++j)
                bfrag[half][kk][j] =
                    (short)Wl[(size_t)(kk * 32 + quad * 8 + j) * DIM + col0 + nidx];
        }
    }

    __syncthreads();  // all hsrc reads complete before any aliased A write

    float4v acc0 = {0.f, 0.f, 0.f, 0.f};
    float4v acc1 = {0.f, 0.f, 0.f, 0.f};
    #pragma unroll
    for (int kk = 0; kk < 4; ++kk) {
        acc0 = __builtin_amdgcn_mfma_f32_16x16x32_bf16(afrag[kk], bfrag[0][kk], acc0, 0, 0, 0);
        acc1 = __builtin_amdgcn_mfma_f32_16x16x32_bf16(afrag[kk], bfrag[1][kk], acc1, 0, 0, 0);
    }

    #pragma unroll
    for (int r = 0; r < 4; ++r) {
        int row = row0 + quad * 4 + r;
        float d = dinv[row];
        float v0 = acc0[r] * d;
        float v1 = acc1[r] * d;
        size_t i0 = (size_t)row * DIM + wave * 32 + nidx;
        size_t i1 = i0 + 16;
        B[i0] = v0;  A[i0] = f32_to_bf16_bits(v0);
        B[i1] = v1;  A[i1] = f32_to_bf16_bits(v1);
    }
}

// ---------------- edge scatter: B[dst] += msg[src] ----------------
__global__ __launch_bounds__(256) void scatter_edges(
    const int* __restrict__ src, const int* __restrict__ dst,
    const unsigned short* __restrict__ A, float* __restrict__ B) {
    int t = blockIdx.x * blockDim.x + threadIdx.x;
    int e = t >> 4;
    if (e >= N_EDGES) return;
    int f = (t & 15) * 8;
    int s = src[e], d = dst[e];
    short8 v = *(const short8*)(A + (size_t)s * DIM + f);
    float* bp = B + (size_t)d * DIM + f;
    #pragma unroll
    for (int j = 0; j < 8; ++j)
        atomicAdd(bp + j, bf16_bits_to_f32((unsigned short)v[j]));
}

// ---------------- BN stats (verified vs oracle in r6) ----------------
__global__ __launch_bounds__(256) void bn_reduce(
    const float* __restrict__ B, const float* __restrict__ dinv,
    const float* __restrict__ bias,  // f32 canonical, layer slice
    float* __restrict__ colsum, float* __restrict__ colsumsq) {
    int c = threadIdx.x & 127;
    int half = threadIdx.x >> 7;
    float bb = bias[c];
    float s = 0.f, s2 = 0.f;
    for (int row = blockIdx.x * 2 + half; row < N_NODES; row += gridDim.x * 2) {
        float v = dinv[row] * B[(size_t)row * DIM + c] + bb;
        s += v;
        s2 += v * v;
    }
    __shared__ float ls[128], ls2[128];
    if (half == 1) { ls[c] = s; ls2[c] = s2; }
    __syncthreads();
    if (half == 0) {
        atomicAdd(&colsum[c], s + ls[c]);
        atomicAdd(&colsumsq[c], s2 + ls2[c]);
    }
}

// ---------------- BN apply + ReLU; output dtype per mode on final layer ----------------
__global__ __launch_bounds__(256) void bn_apply(
    const float* __restrict__ B, const float* __restrict__ dinv,
    const float* __restrict__ prm, int l,   // pf32: b@0, gamma@384, beta@768 (+l*128)
    const float* __restrict__ colsum, const float* __restrict__ colsumsq,
    const float* __restrict__ mode, int is_last,
    void* __restrict__ out) {
    int t = blockIdx.x * blockDim.x + threadIdx.x;
    if (t >= N_NODES * DIM) return;
    int row = t >> 7, c = t & 127;
    const float invN = 1.0f / N_NODES;
    float mu = colsum[c] * invN;
    float var = colsumsq[c] * invN - mu * mu;
    float istd = rsqrtf(var + BN_EPS);
    float vpre = dinv[row] * B[t] + prm[l * 128 + c];
    float vbn = prm[384 + l * 128 + c] * (vpre - mu) * istd + prm[768 + l * 128 + c];
    float r = fmaxf(vbn, 0.f);
    if (is_last) {
        if      (badf(mu) || badf(istd)) r = 300.0f;
        else if (badf(vpre))             r = 200.0f;
        else if (badf(vbn))              r = 100.0f;
    }
    if (is_last && mode[0] > 0.5f)
        ((float*)out)[t] = r;                       // f32 output mode
    else
        ((unsigned short*)out)[t] = f32_to_bf16_bits(r);  // hidden / bf16 output
}

extern "C" void kernel_launch(void* const* d_in, const int* in_sizes, int n_in,
                              void* d_out, int out_size, void* d_ws, size_t ws_size,
                              hipStream_t stream) {
    const void* x  = d_in[0];
    const int*  ei = (const int*)d_in[1];
    const void* W  = d_in[2];
    const void* b  = d_in[3];
    const void* g  = d_in[4];
    const void* be = d_in[5];

    // d_out: bf16 hidden/messages for layers 0-1 (first 12.8MB); final layer
    // writes output in sniffed dtype (f32 fills the full 25.6MB buffer).
    unsigned short* hA = (unsigned short*)d_out;

    char* ws = (char*)d_ws;
    size_t off = 0;
    float* dinv = (float*)(ws + off); off += ((size_t)N_NODES * 4 + 255) & ~255ULL;
    float* B    = (float*)(ws + off); off += (size_t)N_NODES * DIM * 4;
    unsigned short* Wc = (unsigned short*)(ws + off); off += (size_t)3 * DIM * DIM * 2;
    float* pf32 = (float*)(ws + off); off += 3 * 3 * DIM * 4;
    float* colsum   = (float*)(ws + off); off += 128 * 4;
    float* colsumsq = (float*)(ws + off); off += 128 * 4;
    float* mode = (float*)(ws + off); off += 256;

    const int* srcv = ei;            // edge_index[0] (original orientation)
    const int* dstv = ei + N_EDGES;  // edge_index[1]

    // Kernels-only init (hipMemsetAsync kills the stream in this harness).
    sniff<<<1, 256, 0, stream>>>((const unsigned short*)x, mode);
    convert_params<<<(3 * DIM * DIM + 3 * 3 * DIM + 255) / 256, 256, 0, stream>>>(
        W, b, g, be, mode, Wc, pf32);
    zero_buf<<<(N_NODES + 255) / 256, 256, 0, stream>>>(dinv, N_NODES);
    deg_count<<<(N_EDGES + 255) / 256, 256, 0, stream>>>(dstv, dinv);
    make_dinv<<<(N_NODES + 255) / 256, 256, 0, stream>>>(dinv);

    for (int l = 0; l < 3; ++l) {
        const void* hin = (l == 0) ? x : (const void*)hA;
        gemm_scale<<<N_NODES / 16, 256, 0, stream>>>(
            hin, (l == 0) ? 1 : 0, Wc + (size_t)l * DIM * DIM, dinv, mode, hA, B);
        scatter_edges<<<(N_EDGES * 16) / 256, 256, 0, stream>>>(srcv, dstv, hA, B);
        zero_buf<<<1, 256, 0, stream>>>(colsum, 256);  // colsum+colsumsq contiguous
        bn_reduce<<<256, 256, 0, stream>>>(B, dinv, pf32 + l * 128, colsum, colsumsq);
        bn_apply<<<(N_NODES * DIM) / 256, 256, 0, stream>>>(
            B, dinv, pf32, l, colsum, colsumsq, mode, (l == 2) ? 1 : 0, d_out);
    }
}

// Round 8
// 636.765 us; speedup vs baseline: 13.6452x; 13.6452x over previous
//
#include <hip/hip_runtime.h>
#include <hip/hip_bf16.h>

#define N_NODES 50000
#define N_EDGES 800000
#define DIM 128
#define BN_EPS 1e-5f

typedef __attribute__((ext_vector_type(8))) short short8;
typedef __attribute__((ext_vector_type(4))) float float4v;

__device__ __forceinline__ float bf16_bits_to_f32(unsigned short u) {
    union { unsigned int i; float f; } c;
    c.i = ((unsigned int)u) << 16;
    return c.f;
}

__device__ __forceinline__ float bf16_lo(unsigned int u) {
    union { unsigned int i; float f; } c;
    c.i = u << 16;
    return c.f;
}

__device__ __forceinline__ float bf16_hi(unsigned int u) {
    union { unsigned int i; float f; } c;
    c.i = u & 0xFFFF0000u;
    return c.f;
}

__device__ __forceinline__ unsigned short f32_to_bf16_bits(float f) {
    union { float f; unsigned int i; } c;
    c.f = f;
    unsigned int lsb = (c.i >> 16) & 1u;
    c.i += 0x7FFFu + lsb;   // RNE
    return (unsigned short)(c.i >> 16);
}

// ---------------- dtype sniff (r7: inputs are f32; keep adaptive, it's cheap) ----------------
__global__ __launch_bounds__(256) void sniff(const unsigned short* __restrict__ xu,
                                             float* __restrict__ mode) {
    __shared__ int cnt;
    if (threadIdx.x == 0) cnt = 0;
    __syncthreads();
    int ok = 0;
    for (int i = threadIdx.x; i < 512; i += 256) {
        unsigned e = (xu[i] >> 7) & 0xFFu;
        if (e >= 96u && e <= 159u) ok++;
    }
    atomicAdd(&cnt, ok);
    __syncthreads();
    if (threadIdx.x == 0) mode[0] = (cnt >= 480) ? 0.0f : 1.0f;  // 0=bf16, 1=f32
}

// ---------------- zero-init (hipMemsetAsync in kernel_launch kills the stream) ----------------
__global__ __launch_bounds__(256) void zero_buf(float* __restrict__ p, int n) {
    int i = blockIdx.x * blockDim.x + threadIdx.x;
    if (i < n) p[i] = 0.0f;
}

__global__ __launch_bounds__(256) void zero_int(int* __restrict__ p, int n) {
    int i = blockIdx.x * blockDim.x + threadIdx.x;
    if (i < n) p[i] = 0;
}

// ---------------- canonicalize params: W -> bf16 Wc, b/gamma/beta -> f32 pf32 ----------------
__global__ __launch_bounds__(256) void convert_params(
    const void* __restrict__ W, const void* __restrict__ b,
    const void* __restrict__ g, const void* __restrict__ be,
    const float* __restrict__ mode,
    unsigned short* __restrict__ Wc, float* __restrict__ pf32) {
    const bool mf32 = mode[0] > 0.5f;
    int i = blockIdx.x * blockDim.x + threadIdx.x;
    const int NW = 3 * DIM * DIM;  // 49152
    if (i < NW) {
        Wc[i] = mf32 ? f32_to_bf16_bits(((const float*)W)[i])
                     : ((const unsigned short*)W)[i];
    } else if (i < NW + 3 * 3 * DIM) {
        int p = i - NW;
        int which = p / 384;         // 0=b 1=gamma 2=beta
        int r = p - which * 384;
        const void* srcp = (which == 0) ? b : (which == 1) ? g : be;
        float v = mf32 ? ((const float*)srcp)[r]
                       : bf16_bits_to_f32(((const unsigned short*)srcp)[r]);
        pf32[which * 384 + r] = v;
    }
}

// ---------------- in-degree histogram (int) ----------------
__global__ __launch_bounds__(256) void hist_dst(const int* __restrict__ dst,
                                                int* __restrict__ cnt) {
    int e = blockIdx.x * blockDim.x + threadIdx.x;
    if (e < N_EDGES) atomicAdd(&cnt[dst[e]], 1);
}

__global__ __launch_bounds__(256) void make_dinv(const int* __restrict__ cnt,
                                                 float* __restrict__ dinv) {
    int v = blockIdx.x * blockDim.x + threadIdx.x;
    if (v < N_NODES) dinv[v] = rsqrtf((float)cnt[v] + 1.0f);  // +1 self-loop
}

// ---------------- exclusive prefix scan of in-degrees -> row_ptr, next ----------------
// One block, 256 threads, each owns a contiguous chunk of ~196 nodes.
__global__ __launch_bounds__(256) void scan_rowptr(const int* __restrict__ cnt,
                                                   int* __restrict__ row_ptr,
                                                   int* __restrict__ next) {
    __shared__ int sums[256];
    const int chunk = (N_NODES + 255) / 256;  // 196
    const int tid = threadIdx.x;
    const int lo = tid * chunk;
    const int hi = min(lo + chunk, N_NODES);
    int s = 0;
    for (int i = lo; i < hi; ++i) s += cnt[i];
    sums[tid] = s;
    __syncthreads();
    if (tid == 0) {
        int acc = 0;
        for (int i = 0; i < 256; ++i) { int t = sums[i]; sums[i] = acc; acc += t; }
    }
    __syncthreads();
    int run = sums[tid];
    for (int i = lo; i < hi; ++i) {
        row_ptr[i] = run;
        next[i] = run;
        run += cnt[i];
    }
    if (tid == 255) row_ptr[N_NODES] = N_EDGES;
}

// ---------------- CSR fill: col_idx grouped by dst ----------------
__global__ __launch_bounds__(256) void fill_csr(const int* __restrict__ src,
                                                const int* __restrict__ dst,
                                                int* __restrict__ next,
                                                int* __restrict__ col_idx) {
    int e = blockIdx.x * blockDim.x + threadIdx.x;
    if (e < N_EDGES) {
        int pos = atomicAdd(&next[dst[e]], 1);
        col_idx[pos] = src[e];
    }
}

// ---------------- GEMM (MFMA, VALU-verified r5): msg = dinv[row]*(h@W) ----------------
// Writes bf16 msg A (aliases d_out) and fp32 self-init B (used by scatter fallback).
__global__ __launch_bounds__(256) void gemm_scale(
    const void* hsrc, int use_x,
    const unsigned short* __restrict__ Wl,
    const float* __restrict__ dinv,
    const float* __restrict__ mode,
    unsigned short* A, float* __restrict__ B) {
    const int wave = threadIdx.x >> 6;
    const int lane = threadIdx.x & 63;
    const int quad = lane >> 4;
    const int nidx = lane & 15;
    const int row0 = blockIdx.x * 16;
    const bool srcf32 = use_x && (mode[0] > 0.5f);

    short8 afrag[4];
    if (srcf32) {
        const float* xf = (const float*)hsrc;
        #pragma unroll
        for (int kk = 0; kk < 4; ++kk) {
            #pragma unroll
            for (int j = 0; j < 8; ++j)
                afrag[kk][j] = (short)f32_to_bf16_bits(
                    xf[(size_t)(row0 + nidx) * DIM + kk * 32 + quad * 8 + j]);
        }
    } else {
        const unsigned short* hu = (const unsigned short*)hsrc;
        #pragma unroll
        for (int kk = 0; kk < 4; ++kk)
            afrag[kk] = *(const short8*)(hu + (size_t)(row0 + nidx) * DIM + kk * 32 + quad * 8);
    }

    short8 bfrag[2][4];
    #pragma unroll
    for (int half = 0; half < 2; ++half) {
        int col0 = wave * 32 + half * 16;
        #pragma unroll
        for (int kk = 0; kk < 4; ++kk) {
            #pragma unroll
            for (int j = 0; j < 8; ++j)
                bfrag[half][kk][j] =
                    (short)Wl[(size_t)(kk * 32 + quad * 8 + j) * DIM + col0 + nidx];
        }
    }

    __syncthreads();  // all hsrc reads complete before any aliased A write

    float4v acc0 = {0.f, 0.f, 0.f, 0.f};
    float4v acc1 = {0.f, 0.f, 0.f, 0.f};
    #pragma unroll
    for (int kk = 0; kk < 4; ++kk) {
        acc0 = __builtin_amdgcn_mfma_f32_16x16x32_bf16(afrag[kk], bfrag[0][kk], acc0, 0, 0, 0);
        acc1 = __builtin_amdgcn_mfma_f32_16x16x32_bf16(afrag[kk], bfrag[1][kk], acc1, 0, 0, 0);
    }

    #pragma unroll
    for (int r = 0; r < 4; ++r) {
        int row = row0 + quad * 4 + r;
        float d = dinv[row];
        float v0 = acc0[r] * d;
        float v1 = acc1[r] * d;
        size_t i0 = (size_t)row * DIM + wave * 32 + nidx;
        size_t i1 = i0 + 16;
        B[i0] = v0;  A[i0] = f32_to_bf16_bits(v0);
        B[i1] = v1;  A[i1] = f32_to_bf16_bits(v1);
    }
}

// ---------------- CSR gather: B[v] = A[v] + sum_{in-edges} A[src]  (NO atomics) ----------------
// One wave per destination node; lane covers 2 columns (4B bf16x2 load, 8B f32x2 store).
__global__ __launch_bounds__(256) void gather_csr(
    const int* __restrict__ row_ptr, const int* __restrict__ col_idx,
    const unsigned short* __restrict__ A, float* __restrict__ B) {
    const int wave = threadIdx.x >> 6;
    const int lane = threadIdx.x & 63;
    const int node = blockIdx.x * 4 + wave;
    if (node >= N_NODES) return;
    const int lo = row_ptr[node];
    const int hi = row_ptr[node + 1];

    unsigned int su = *(const unsigned int*)(A + (size_t)node * DIM + lane * 2);
    float a0 = bf16_lo(su), a1 = bf16_hi(su);

    int e = lo;
    for (; e + 2 <= hi; e += 2) {
        int s0 = col_idx[e];
        int s1 = col_idx[e + 1];
        unsigned int v0 = *(const unsigned int*)(A + (size_t)s0 * DIM + lane * 2);
        unsigned int v1 = *(const unsigned int*)(A + (size_t)s1 * DIM + lane * 2);
        a0 += bf16_lo(v0); a1 += bf16_hi(v0);
        a0 += bf16_lo(v1); a1 += bf16_hi(v1);
    }
    if (e < hi) {
        int s0 = col_idx[e];
        unsigned int v0 = *(const unsigned int*)(A + (size_t)s0 * DIM + lane * 2);
        a0 += bf16_lo(v0); a1 += bf16_hi(v0);
    }

    float2 st = {a0, a1};
    *(float2*)(B + (size_t)node * DIM + lane * 2) = st;
}

// ---------------- scatter fallback (r7-proven, used only if ws too small) ----------------
__global__ __launch_bounds__(256) void scatter_edges(
    const int* __restrict__ src, const int* __restrict__ dst,
    const unsigned short* __restrict__ A, float* __restrict__ B) {
    int t = blockIdx.x * blockDim.x + threadIdx.x;
    int e = t >> 4;
    if (e >= N_EDGES) return;
    int f = (t & 15) * 8;
    int s = src[e], d = dst[e];
    short8 v = *(const short8*)(A + (size_t)s * DIM + f);
    float* bp = B + (size_t)d * DIM + f;
    #pragma unroll
    for (int j = 0; j < 8; ++j)
        atomicAdd(bp + j, bf16_bits_to_f32((unsigned short)v[j]));
}

// ---------------- BN stats (oracle-verified r6) ----------------
__global__ __launch_bounds__(256) void bn_reduce(
    const float* __restrict__ B, const float* __restrict__ dinv,
    const float* __restrict__ bias,
    float* __restrict__ colsum, float* __restrict__ colsumsq) {
    int c = threadIdx.x & 127;
    int half = threadIdx.x >> 7;
    float bb = bias[c];
    float s = 0.f, s2 = 0.f;
    for (int row = blockIdx.x * 2 + half; row < N_NODES; row += gridDim.x * 2) {
        float v = dinv[row] * B[(size_t)row * DIM + c] + bb;
        s += v;
        s2 += v * v;
    }
    __shared__ float ls[128], ls2[128];
    if (half == 1) { ls[c] = s; ls2[c] = s2; }
    __syncthreads();
    if (half == 0) {
        atomicAdd(&colsum[c], s + ls[c]);
        atomicAdd(&colsumsq[c], s2 + ls2[c]);
    }
}

// ---------------- BN apply + ReLU; output dtype per mode on final layer ----------------
__global__ __launch_bounds__(256) void bn_apply(
    const float* __restrict__ B, const float* __restrict__ dinv,
    const float* __restrict__ prm, int l,
    const float* __restrict__ colsum, const float* __restrict__ colsumsq,
    const float* __restrict__ mode, int is_last,
    void* __restrict__ out) {
    int t = blockIdx.x * blockDim.x + threadIdx.x;
    if (t >= N_NODES * DIM) return;
    int row = t >> 7, c = t & 127;
    const float invN = 1.0f / N_NODES;
    float mu = colsum[c] * invN;
    float var = colsumsq[c] * invN - mu * mu;
    float istd = rsqrtf(var + BN_EPS);
    float vpre = dinv[row] * B[t] + prm[l * 128 + c];
    float vbn = prm[384 + l * 128 + c] * (vpre - mu) * istd + prm[768 + l * 128 + c];
    float r = fmaxf(vbn, 0.f);
    if (is_last && mode[0] > 0.5f)
        ((float*)out)[t] = r;
    else
        ((unsigned short*)out)[t] = f32_to_bf16_bits(r);
}

extern "C" void kernel_launch(void* const* d_in, const int* in_sizes, int n_in,
                              void* d_out, int out_size, void* d_ws, size_t ws_size,
                              hipStream_t stream) {
    const void* x  = d_in[0];
    const int*  ei = (const int*)d_in[1];
    const void* W  = d_in[2];
    const void* b  = d_in[3];
    const void* g  = d_in[4];
    const void* be = d_in[5];

    unsigned short* hA = (unsigned short*)d_out;  // bf16 msg / hidden buffer

    char* ws = (char*)d_ws;
    size_t off = 0;
    auto alloc = [&](size_t bytes) {
        char* p = ws + off;
        off = (off + bytes + 255) & ~(size_t)255;
        return p;
    };
    float* dinv     = (float*)alloc((size_t)N_NODES * 4);
    float* B        = (float*)alloc((size_t)N_NODES * DIM * 4);
    unsigned short* Wc = (unsigned short*)alloc((size_t)3 * DIM * DIM * 2);
    float* pf32     = (float*)alloc(3 * 3 * DIM * 4);
    float* colsum   = (float*)alloc(128 * 4);
    float* colsumsq = (float*)alloc(128 * 4);
    float* mode     = (float*)alloc(64 * 4);
    int*   cnt      = (int*)alloc((size_t)N_NODES * 4);
    size_t base_needed = off;                       // scatter-fallback footprint
    int*   row_ptr  = (int*)alloc((size_t)(N_NODES + 1) * 4);
    int*   next     = (int*)alloc((size_t)N_NODES * 4);
    int*   col_idx  = (int*)alloc((size_t)N_EDGES * 4);
    const bool csr_ok = (ws_size >= off) || (ws_size == 0);
    (void)base_needed;

    const int* srcv = ei;            // edge_index[0]
    const int* dstv = ei + N_EDGES;  // edge_index[1]

    sniff<<<1, 256, 0, stream>>>((const unsigned short*)x, mode);
    convert_params<<<(3 * DIM * DIM + 3 * 3 * DIM + 255) / 256, 256, 0, stream>>>(
        W, b, g, be, mode, Wc, pf32);
    zero_int<<<(N_NODES + 255) / 256, 256, 0, stream>>>(cnt, N_NODES);
    hist_dst<<<(N_EDGES + 255) / 256, 256, 0, stream>>>(dstv, cnt);
    make_dinv<<<(N_NODES + 255) / 256, 256, 0, stream>>>(cnt, dinv);
    if (csr_ok) {
        scan_rowptr<<<1, 256, 0, stream>>>(cnt, row_ptr, next);
        fill_csr<<<(N_EDGES + 255) / 256, 256, 0, stream>>>(srcv, dstv, next, col_idx);
    }

    for (int l = 0; l < 3; ++l) {
        const void* hin = (l == 0) ? x : (const void*)hA;
        gemm_scale<<<N_NODES / 16, 256, 0, stream>>>(
            hin, (l == 0) ? 1 : 0, Wc + (size_t)l * DIM * DIM, dinv, mode, hA, B);
        if (csr_ok)
            gather_csr<<<(N_NODES + 3) / 4, 256, 0, stream>>>(row_ptr, col_idx, hA, B);
        else
            scatter_edges<<<(N_EDGES * 16) / 256, 256, 0, stream>>>(srcv, dstv, hA, B);
        zero_buf<<<1, 256, 0, stream>>>(colsum, 256);
        bn_reduce<<<256, 256, 0, stream>>>(B, dinv, pf32 + l * 128, colsum, colsumsq);
        bn_apply<<<(N_NODES * DIM) / 256, 256, 0, stream>>>(
            B, dinv, pf32, l, colsum, colsumsq, mode, (l == 2) ? 1 : 0, d_out);
    }
}

// Round 9
// 518.813 us; speedup vs baseline: 16.7474x; 1.2273x over previous
//
#include <hip/hip_runtime.h>
#include <hip/hip_bf16.h>

#define N_NODES 50000
#define N_EDGES 800000
#define DIM 128
#define BN_EPS 1e-5f
#define SCAN_BLOCKS ((N_NODES + 255) / 256)   // 196

typedef __attribute__((ext_vector_type(8))) short short8;
typedef __attribute__((ext_vector_type(4))) float float4v;

__device__ __forceinline__ float bf16_bits_to_f32(unsigned short u) {
    union { unsigned int i; float f; } c;
    c.i = ((unsigned int)u) << 16;
    return c.f;
}

__device__ __forceinline__ float bf16_lo(unsigned int u) {
    union { unsigned int i; float f; } c;
    c.i = u << 16;
    return c.f;
}

__device__ __forceinline__ float bf16_hi(unsigned int u) {
    union { unsigned int i; float f; } c;
    c.i = u & 0xFFFF0000u;
    return c.f;
}

__device__ __forceinline__ unsigned short f32_to_bf16_bits(float f) {
    union { float f; unsigned int i; } c;
    c.f = f;
    unsigned int lsb = (c.i >> 16) & 1u;
    c.i += 0x7FFFu + lsb;   // RNE
    return (unsigned short)(c.i >> 16);
}

// ---------------- dtype sniff (r7: inputs are f32; adaptive, cheap) ----------------
__global__ __launch_bounds__(256) void sniff(const unsigned short* __restrict__ xu,
                                             float* __restrict__ mode) {
    __shared__ int cnt;
    if (threadIdx.x == 0) cnt = 0;
    __syncthreads();
    int ok = 0;
    for (int i = threadIdx.x; i < 512; i += 256) {
        unsigned e = (xu[i] >> 7) & 0xFFu;
        if (e >= 96u && e <= 159u) ok++;
    }
    atomicAdd(&cnt, ok);
    __syncthreads();
    if (threadIdx.x == 0) mode[0] = (cnt >= 480) ? 0.0f : 1.0f;  // 0=bf16, 1=f32
}

// ---------------- zero-init (hipMemsetAsync in kernel_launch kills the stream) ----------------
__global__ __launch_bounds__(256) void zero_buf(float* __restrict__ p, int n) {
    int i = blockIdx.x * blockDim.x + threadIdx.x;
    if (i < n) p[i] = 0.0f;
}

__global__ __launch_bounds__(256) void zero_int(int* __restrict__ p, int n) {
    int i = blockIdx.x * blockDim.x + threadIdx.x;
    if (i < n) p[i] = 0;
}

// ---------------- canonicalize params: W -> bf16 Wc, b/gamma/beta -> f32 pf32 ----------------
__global__ __launch_bounds__(256) void convert_params(
    const void* __restrict__ W, const void* __restrict__ b,
    const void* __restrict__ g, const void* __restrict__ be,
    const float* __restrict__ mode,
    unsigned short* __restrict__ Wc, float* __restrict__ pf32) {
    const bool mf32 = mode[0] > 0.5f;
    int i = blockIdx.x * blockDim.x + threadIdx.x;
    const int NW = 3 * DIM * DIM;  // 49152
    if (i < NW) {
        Wc[i] = mf32 ? f32_to_bf16_bits(((const float*)W)[i])
                     : ((const unsigned short*)W)[i];
    } else if (i < NW + 3 * 3 * DIM) {
        int p = i - NW;
        int which = p / 384;         // 0=b 1=gamma 2=beta
        int r = p - which * 384;
        const void* srcp = (which == 0) ? b : (which == 1) ? g : be;
        float v = mf32 ? ((const float*)srcp)[r]
                       : bf16_bits_to_f32(((const unsigned short*)srcp)[r]);
        pf32[which * 384 + r] = v;
    }
}

// ---------------- in-degree histogram (int) ----------------
__global__ __launch_bounds__(256) void hist_dst(const int* __restrict__ dst,
                                                int* __restrict__ cnt) {
    int e = blockIdx.x * blockDim.x + threadIdx.x;
    if (e < N_EDGES) atomicAdd(&cnt[dst[e]], 1);
}

// ---------------- hierarchical scan: K1 per-block sums (coalesced tree-reduce) ----------------
__global__ __launch_bounds__(256) void block_sums(const int* __restrict__ cnt,
                                                  int* __restrict__ bsum) {
    __shared__ int s[256];
    const int tid = threadIdx.x;
    int i = blockIdx.x * 256 + tid;
    s[tid] = (i < N_NODES) ? cnt[i] : 0;
    __syncthreads();
    #pragma unroll
    for (int o = 128; o > 0; o >>= 1) {
        if (tid < o) s[tid] += s[tid + o];
        __syncthreads();
    }
    if (tid == 0) bsum[blockIdx.x] = s[0];
}

// ---------------- K2: exclusive scan of the 196 block sums (1 block, LDS) ----------------
__global__ __launch_bounds__(256) void scan_bsums(int* __restrict__ bsum) {
    __shared__ int s[256];
    const int tid = threadIdx.x;
    int v = (tid < SCAN_BLOCKS) ? bsum[tid] : 0;
    s[tid] = v;
    __syncthreads();
    #pragma unroll
    for (int o = 1; o < 256; o <<= 1) {
        int t = (tid >= o) ? s[tid - o] : 0;
        __syncthreads();
        s[tid] += t;
        __syncthreads();
    }
    if (tid < SCAN_BLOCKS) bsum[tid] = s[tid] - v;  // exclusive
}

// ---------------- K3: per-block scan + offset -> row_ptr/next; fused make_dinv ----------------
__global__ __launch_bounds__(256) void scan_final(const int* __restrict__ cnt,
                                                  const int* __restrict__ bsum,
                                                  int* __restrict__ row_ptr,
                                                  int* __restrict__ next,
                                                  float* __restrict__ dinv) {
    __shared__ int s[256];
    const int tid = threadIdx.x;
    int i = blockIdx.x * 256 + tid;
    int v = (i < N_NODES) ? cnt[i] : 0;
    s[tid] = v;
    __syncthreads();
    #pragma unroll
    for (int o = 1; o < 256; o <<= 1) {
        int t = (tid >= o) ? s[tid - o] : 0;
        __syncthreads();
        s[tid] += t;
        __syncthreads();
    }
    if (i < N_NODES) {
        int excl = s[tid] - v + bsum[blockIdx.x];
        row_ptr[i] = excl;
        next[i] = excl;
        dinv[i] = rsqrtf((float)v + 1.0f);  // +1 self-loop (fused make_dinv)
    }
    if (i == N_NODES - 1) row_ptr[N_NODES] = N_EDGES;
}

// ---------------- CSR fill: col_idx grouped by dst ----------------
__global__ __launch_bounds__(256) void fill_csr(const int* __restrict__ src,
                                                const int* __restrict__ dst,
                                                int* __restrict__ next,
                                                int* __restrict__ col_idx) {
    int e = blockIdx.x * blockDim.x + threadIdx.x;
    if (e < N_EDGES) {
        int pos = atomicAdd(&next[dst[e]], 1);
        col_idx[pos] = src[e];
    }
}

// ---------------- GEMM (MFMA, VALU-verified r5): msg = dinv[row]*(h@W) ----------------
__global__ __launch_bounds__(256) void gemm_scale(
    const void* hsrc, int use_x,
    const unsigned short* __restrict__ Wl,
    const float* __restrict__ dinv,
    const float* __restrict__ mode,
    unsigned short* A, float* __restrict__ B) {
    const int wave = threadIdx.x >> 6;
    const int lane = threadIdx.x & 63;
    const int quad = lane >> 4;
    const int nidx = lane & 15;
    const int row0 = blockIdx.x * 16;
    const bool srcf32 = use_x && (mode[0] > 0.5f);

    short8 afrag[4];
    if (srcf32) {
        const float* xf = (const float*)hsrc;
        #pragma unroll
        for (int kk = 0; kk < 4; ++kk) {
            #pragma unroll
            for (int j = 0; j < 8; ++j)
                afrag[kk][j] = (short)f32_to_bf16_bits(
                    xf[(size_t)(row0 + nidx) * DIM + kk * 32 + quad * 8 + j]);
        }
    } else {
        const unsigned short* hu = (const unsigned short*)hsrc;
        #pragma unroll
        for (int kk = 0; kk < 4; ++kk)
            afrag[kk] = *(const short8*)(hu + (size_t)(row0 + nidx) * DIM + kk * 32 + quad * 8);
    }

    short8 bfrag[2][4];
    #pragma unroll
    for (int half = 0; half < 2; ++half) {
        int col0 = wave * 32 + half * 16;
        #pragma unroll
        for (int kk = 0; kk < 4; ++kk) {
            #pragma unroll
            for (int j = 0; j < 8; ++j)
                bfrag[half][kk][j] =
                    (short)Wl[(size_t)(kk * 32 + quad * 8 + j) * DIM + col0 + nidx];
        }
    }

    __syncthreads();  // all hsrc reads complete before any aliased A write

    float4v acc0 = {0.f, 0.f, 0.f, 0.f};
    float4v acc1 = {0.f, 0.f, 0.f, 0.f};
    #pragma unroll
    for (int kk = 0; kk < 4; ++kk) {
        acc0 = __builtin_amdgcn_mfma_f32_16x16x32_bf16(afrag[kk], bfrag[0][kk], acc0, 0, 0, 0);
        acc1 = __builtin_amdgcn_mfma_f32_16x16x32_bf16(afrag[kk], bfrag[1][kk], acc1, 0, 0, 0);
    }

    #pragma unroll
    for (int r = 0; r < 4; ++r) {
        int row = row0 + quad * 4 + r;
        float d = dinv[row];
        float v0 = acc0[r] * d;
        float v1 = acc1[r] * d;
        size_t i0 = (size_t)row * DIM + wave * 32 + nidx;
        size_t i1 = i0 + 16;
        B[i0] = v0;  A[i0] = f32_to_bf16_bits(v0);
        B[i1] = v1;  A[i1] = f32_to_bf16_bits(v1);
    }
}

// ---------------- CSR gather: B[v] = A[v] + sum_{in-edges} A[src]  (NO atomics) ----------------
__global__ __launch_bounds__(256) void gather_csr(
    const int* __restrict__ row_ptr, const int* __restrict__ col_idx,
    const unsigned short* __restrict__ A, float* __restrict__ B) {
    const int wave = threadIdx.x >> 6;
    const int lane = threadIdx.x & 63;
    const int node = blockIdx.x * 4 + wave;
    if (node >= N_NODES) return;
    const int lo = row_ptr[node];
    const int hi = row_ptr[node + 1];

    unsigned int su = *(const unsigned int*)(A + (size_t)node * DIM + lane * 2);
    float a0 = bf16_lo(su), a1 = bf16_hi(su);

    int e = lo;
    for (; e + 2 <= hi; e += 2) {
        int s0 = col_idx[e];
        int s1 = col_idx[e + 1];
        unsigned int v0 = *(const unsigned int*)(A + (size_t)s0 * DIM + lane * 2);
        unsigned int v1 = *(const unsigned int*)(A + (size_t)s1 * DIM + lane * 2);
        a0 += bf16_lo(v0); a1 += bf16_hi(v0);
        a0 += bf16_lo(v1); a1 += bf16_hi(v1);
    }
    if (e < hi) {
        int s0 = col_idx[e];
        unsigned int v0 = *(const unsigned int*)(A + (size_t)s0 * DIM + lane * 2);
        a0 += bf16_lo(v0); a1 += bf16_hi(v0);
    }

    float2 st = {a0, a1};
    *(float2*)(B + (size_t)node * DIM + lane * 2) = st;
}

// ---------------- scatter fallback (r7-proven, used only if ws too small) ----------------
__global__ __launch_bounds__(256) void scatter_edges(
    const int* __restrict__ src, const int* __restrict__ dst,
    const unsigned short* __restrict__ A, float* __restrict__ B) {
    int t = blockIdx.x * blockDim.x + threadIdx.x;
    int e = t >> 4;
    if (e >= N_EDGES) return;
    int f = (t & 15) * 8;
    int s = src[e], d = dst[e];
    short8 v = *(const short8*)(A + (size_t)s * DIM + f);
    float* bp = B + (size_t)d * DIM + f;
    #pragma unroll
    for (int j = 0; j < 8; ++j)
        atomicAdd(bp + j, bf16_bits_to_f32((unsigned short)v[j]));
}

// fallback needs dinv/next even without CSR kernels
__global__ __launch_bounds__(256) void make_dinv(const int* __restrict__ cnt,
                                                 float* __restrict__ dinv) {
    int v = blockIdx.x * blockDim.x + threadIdx.x;
    if (v < N_NODES) dinv[v] = rsqrtf((float)cnt[v] + 1.0f);
}

// ---------------- BN stats (oracle-verified r6) ----------------
__global__ __launch_bounds__(256) void bn_reduce(
    const float* __restrict__ B, const float* __restrict__ dinv,
    const float* __restrict__ bias,
    float* __restrict__ colsum, float* __restrict__ colsumsq) {
    int c = threadIdx.x & 127;
    int half = threadIdx.x >> 7;
    float bb = bias[c];
    float s = 0.f, s2 = 0.f;
    for (int row = blockIdx.x * 2 + half; row < N_NODES; row += gridDim.x * 2) {
        float v = dinv[row] * B[(size_t)row * DIM + c] + bb;
        s += v;
        s2 += v * v;
    }
    __shared__ float ls[128], ls2[128];
    if (half == 1) { ls[c] = s; ls2[c] = s2; }
    __syncthreads();
    if (half == 0) {
        atomicAdd(&colsum[c], s + ls[c]);
        atomicAdd(&colsumsq[c], s2 + ls2[c]);
    }
}

// ---------------- BN apply + ReLU; output dtype per mode on final layer ----------------
__global__ __launch_bounds__(256) void bn_apply(
    const float* __restrict__ B, const float* __restrict__ dinv,
    const float* __restrict__ prm, int l,
    const float* __restrict__ colsum, const float* __restrict__ colsumsq,
    const float* __restrict__ mode, int is_last,
    void* __restrict__ out) {
    int t = blockIdx.x * blockDim.x + threadIdx.x;
    if (t >= N_NODES * DIM) return;
    int row = t >> 7, c = t & 127;
    const float invN = 1.0f / N_NODES;
    float mu = colsum[c] * invN;
    float var = colsumsq[c] * invN - mu * mu;
    float istd = rsqrtf(var + BN_EPS);
    float vpre = dinv[row] * B[t] + prm[l * 128 + c];
    float vbn = prm[384 + l * 128 + c] * (vpre - mu) * istd + prm[768 + l * 128 + c];
    float r = fmaxf(vbn, 0.f);
    if (is_last && mode[0] > 0.5f)
        ((float*)out)[t] = r;
    else
        ((unsigned short*)out)[t] = f32_to_bf16_bits(r);
}

extern "C" void kernel_launch(void* const* d_in, const int* in_sizes, int n_in,
                              void* d_out, int out_size, void* d_ws, size_t ws_size,
                              hipStream_t stream) {
    const void* x  = d_in[0];
    const int*  ei = (const int*)d_in[1];
    const void* W  = d_in[2];
    const void* b  = d_in[3];
    const void* g  = d_in[4];
    const void* be = d_in[5];

    unsigned short* hA = (unsigned short*)d_out;  // bf16 msg / hidden buffer

    char* ws = (char*)d_ws;
    size_t off = 0;
    auto alloc = [&](size_t bytes) {
        char* p = ws + off;
        off = (off + bytes + 255) & ~(size_t)255;
        return p;
    };
    float* dinv     = (float*)alloc((size_t)N_NODES * 4);
    float* B        = (float*)alloc((size_t)N_NODES * DIM * 4);
    unsigned short* Wc = (unsigned short*)alloc((size_t)3 * DIM * DIM * 2);
    float* pf32     = (float*)alloc(3 * 3 * DIM * 4);
    float* colsum   = (float*)alloc(128 * 4);
    float* colsumsq = (float*)alloc(128 * 4);
    float* mode     = (float*)alloc(64 * 4);
    int*   cnt      = (int*)alloc((size_t)N_NODES * 4);
    int*   row_ptr  = (int*)alloc((size_t)(N_NODES + 1) * 4);
    int*   next     = (int*)alloc((size_t)N_NODES * 4);
    int*   bsum     = (int*)alloc(256 * 4);
    int*   col_idx  = (int*)alloc((size_t)N_EDGES * 4);
    const bool csr_ok = (ws_size >= off) || (ws_size == 0);

    const int* srcv = ei;            // edge_index[0]
    const int* dstv = ei + N_EDGES;  // edge_index[1]

    sniff<<<1, 256, 0, stream>>>((const unsigned short*)x, mode);
    convert_params<<<(3 * DIM * DIM + 3 * 3 * DIM + 255) / 256, 256, 0, stream>>>(
        W, b, g, be, mode, Wc, pf32);
    zero_int<<<(N_NODES + 255) / 256, 256, 0, stream>>>(cnt, N_NODES);
    hist_dst<<<(N_EDGES + 255) / 256, 256, 0, stream>>>(dstv, cnt);
    if (csr_ok) {
        block_sums<<<SCAN_BLOCKS, 256, 0, stream>>>(cnt, bsum);
        scan_bsums<<<1, 256, 0, stream>>>(bsum);
        scan_final<<<SCAN_BLOCKS, 256, 0, stream>>>(cnt, bsum, row_ptr, next, dinv);
        fill_csr<<<(N_EDGES + 255) / 256, 256, 0, stream>>>(srcv, dstv, next, col_idx);
    } else {
        make_dinv<<<(N_NODES + 255) / 256, 256, 0, stream>>>(cnt, dinv);
    }

    for (int l = 0; l < 3; ++l) {
        const void* hin = (l == 0) ? x : (const void*)hA;
        gemm_scale<<<N_NODES / 16, 256, 0, stream>>>(
            hin, (l == 0) ? 1 : 0, Wc + (size_t)l * DIM * DIM, dinv, mode, hA, B);
        if (csr_ok)
            gather_csr<<<(N_NODES + 3) / 4, 256, 0, stream>>>(row_ptr, col_idx, hA, B);
        else
            scatter_edges<<<(N_EDGES * 16) / 256, 256, 0, stream>>>(srcv, dstv, hA, B);
        zero_buf<<<1, 256, 0, stream>>>(colsum, 256);
        bn_reduce<<<256, 256, 0, stream>>>(B, dinv, pf32 + l * 128, colsum, colsumsq);
        bn_apply<<<(N_NODES * DIM) / 256, 256, 0, stream>>>(
            B, dinv, pf32, l, colsum, colsumsq, mode, (l == 2) ? 1 : 0, d_out);
    }
}

// Round 10
// 494.076 us; speedup vs baseline: 17.5859x; 1.0501x over previous
//
#include <hip/hip_runtime.h>
#include <hip/hip_bf16.h>

#define N_NODES 50000
#define N_EDGES 800000
#define DIM 128
#define BN_EPS 1e-5f
#define SCAN_BLOCKS ((N_NODES + 255) / 256)   // 196

typedef __attribute__((ext_vector_type(8))) short short8;
typedef __attribute__((ext_vector_type(4))) float float4v;

__device__ __forceinline__ float bf16_bits_to_f32(unsigned short u) {
    union { unsigned int i; float f; } c;
    c.i = ((unsigned int)u) << 16;
    return c.f;
}

__device__ __forceinline__ float bf16_lo(unsigned int u) {
    union { unsigned int i; float f; } c;
    c.i = u << 16;
    return c.f;
}

__device__ __forceinline__ float bf16_hi(unsigned int u) {
    union { unsigned int i; float f; } c;
    c.i = u & 0xFFFF0000u;
    return c.f;
}

__device__ __forceinline__ unsigned short f32_to_bf16_bits(float f) {
    union { float f; unsigned int i; } c;
    c.f = f;
    unsigned int lsb = (c.i >> 16) & 1u;
    c.i += 0x7FFFu + lsb;   // RNE
    return (unsigned short)(c.i >> 16);
}

// ---------------- dtype sniff (r7: inputs are f32; adaptive, cheap) ----------------
__global__ __launch_bounds__(256) void sniff(const unsigned short* __restrict__ xu,
                                             float* __restrict__ mode) {
    __shared__ int cnt;
    if (threadIdx.x == 0) cnt = 0;
    __syncthreads();
    int ok = 0;
    for (int i = threadIdx.x; i < 512; i += 256) {
        unsigned e = (xu[i] >> 7) & 0xFFu;
        if (e >= 96u && e <= 159u) ok++;
    }
    atomicAdd(&cnt, ok);
    __syncthreads();
    if (threadIdx.x == 0) mode[0] = (cnt >= 480) ? 0.0f : 1.0f;  // 0=bf16, 1=f32
}

// ---------------- zero-init (hipMemsetAsync in kernel_launch kills the stream) ----------------
__global__ __launch_bounds__(256) void zero_buf(float* __restrict__ p, int n) {
    int i = blockIdx.x * blockDim.x + threadIdx.x;
    if (i < n) p[i] = 0.0f;
}

__global__ __launch_bounds__(256) void zero_int(int* __restrict__ p, int n) {
    int i = blockIdx.x * blockDim.x + threadIdx.x;
    if (i < n) p[i] = 0;
}

// ---------------- canonicalize params: W -> TRANSPOSED bf16 Wt[n][k]; b/g/be -> f32 ----------------
__global__ __launch_bounds__(256) void convert_params(
    const void* __restrict__ W, const void* __restrict__ b,
    const void* __restrict__ g, const void* __restrict__ be,
    const float* __restrict__ mode,
    unsigned short* __restrict__ Wt, float* __restrict__ pf32) {
    const bool mf32 = mode[0] > 0.5f;
    int i = blockIdx.x * blockDim.x + threadIdx.x;
    const int NW = 3 * DIM * DIM;  // 49152
    if (i < NW) {
        int l = i >> 14;            // /16384
        int rem = i & 16383;
        int k = rem >> 7;           // row in original W
        int n = rem & 127;          // col in original W
        unsigned short v = mf32 ? f32_to_bf16_bits(((const float*)W)[i])
                                : ((const unsigned short*)W)[i];
        Wt[(size_t)l * DIM * DIM + (size_t)n * DIM + k] = v;  // transposed
    } else if (i < NW + 3 * 3 * DIM) {
        int p = i - NW;
        int which = p / 384;         // 0=b 1=gamma 2=beta
        int r = p - which * 384;
        const void* srcp = (which == 0) ? b : (which == 1) ? g : be;
        float v = mf32 ? ((const float*)srcp)[r]
                       : bf16_bits_to_f32(((const unsigned short*)srcp)[r]);
        pf32[which * 384 + r] = v;
    }
}

// ---------------- in-degree histogram (int) ----------------
__global__ __launch_bounds__(256) void hist_dst(const int* __restrict__ dst,
                                                int* __restrict__ cnt) {
    int e = blockIdx.x * blockDim.x + threadIdx.x;
    if (e < N_EDGES) atomicAdd(&cnt[dst[e]], 1);
}

// ---------------- hierarchical scan (r9-verified) ----------------
__global__ __launch_bounds__(256) void block_sums(const int* __restrict__ cnt,
                                                  int* __restrict__ bsum) {
    __shared__ int s[256];
    const int tid = threadIdx.x;
    int i = blockIdx.x * 256 + tid;
    s[tid] = (i < N_NODES) ? cnt[i] : 0;
    __syncthreads();
    #pragma unroll
    for (int o = 128; o > 0; o >>= 1) {
        if (tid < o) s[tid] += s[tid + o];
        __syncthreads();
    }
    if (tid == 0) bsum[blockIdx.x] = s[0];
}

__global__ __launch_bounds__(256) void scan_bsums(int* __restrict__ bsum) {
    __shared__ int s[256];
    const int tid = threadIdx.x;
    int v = (tid < SCAN_BLOCKS) ? bsum[tid] : 0;
    s[tid] = v;
    __syncthreads();
    #pragma unroll
    for (int o = 1; o < 256; o <<= 1) {
        int t = (tid >= o) ? s[tid - o] : 0;
        __syncthreads();
        s[tid] += t;
        __syncthreads();
    }
    if (tid < SCAN_BLOCKS) bsum[tid] = s[tid] - v;  // exclusive
}

__global__ __launch_bounds__(256) void scan_final(const int* __restrict__ cnt,
                                                  const int* __restrict__ bsum,
                                                  int* __restrict__ row_ptr,
                                                  int* __restrict__ next,
                                                  float* __restrict__ dinv) {
    __shared__ int s[256];
    const int tid = threadIdx.x;
    int i = blockIdx.x * 256 + tid;
    int v = (i < N_NODES) ? cnt[i] : 0;
    s[tid] = v;
    __syncthreads();
    #pragma unroll
    for (int o = 1; o < 256; o <<= 1) {
        int t = (tid >= o) ? s[tid - o] : 0;
        __syncthreads();
        s[tid] += t;
        __syncthreads();
    }
    if (i < N_NODES) {
        int excl = s[tid] - v + bsum[blockIdx.x];
        row_ptr[i] = excl;
        next[i] = excl;
        dinv[i] = rsqrtf((float)v + 1.0f);  // +1 self-loop
    }
    if (i == N_NODES - 1) row_ptr[N_NODES] = N_EDGES;
}

// ---------------- CSR fill ----------------
__global__ __launch_bounds__(256) void fill_csr(const int* __restrict__ src,
                                                const int* __restrict__ dst,
                                                int* __restrict__ next,
                                                int* __restrict__ col_idx) {
    int e = blockIdx.x * blockDim.x + threadIdx.x;
    if (e < N_EDGES) {
        int pos = atomicAdd(&next[dst[e]], 1);
        col_idx[pos] = src[e];
    }
}

// ---------------- GEMM (MFMA, VALU-verified r5): msg = dinv[row]*(h@W) ----------------
// Wt is TRANSPOSED [n][k] -> B-fragments are contiguous 16B loads (like A).
// write_b: only the scatter fallback needs the fp32 self-init in B.
__global__ __launch_bounds__(256) void gemm_scale(
    const void* hsrc, int use_x,
    const unsigned short* __restrict__ Wt,
    const float* __restrict__ dinv,
    const float* __restrict__ mode,
    unsigned short* A, float* __restrict__ B, int write_b) {
    const int wave = threadIdx.x >> 6;
    const int lane = threadIdx.x & 63;
    const int quad = lane >> 4;
    const int nidx = lane & 15;
    const int row0 = blockIdx.x * 16;
    const bool srcf32 = use_x && (mode[0] > 0.5f);

    short8 afrag[4];
    if (srcf32) {
        const float* xf = (const float*)hsrc;
        #pragma unroll
        for (int kk = 0; kk < 4; ++kk) {
            const float4v* xr = (const float4v*)(xf + (size_t)(row0 + nidx) * DIM + kk * 32 + quad * 8);
            float4v p0 = xr[0], p1 = xr[1];
            #pragma unroll
            for (int j = 0; j < 4; ++j) {
                afrag[kk][j]     = (short)f32_to_bf16_bits(p0[j]);
                afrag[kk][4 + j] = (short)f32_to_bf16_bits(p1[j]);
            }
        }
    } else {
        const unsigned short* hu = (const unsigned short*)hsrc;
        #pragma unroll
        for (int kk = 0; kk < 4; ++kk)
            afrag[kk] = *(const short8*)(hu + (size_t)(row0 + nidx) * DIM + kk * 32 + quad * 8);
    }

    // B-fragment: B[k][n] with n = col0+nidx, k = kk*32+quad*8+j -> contiguous in Wt[n][k]
    short8 bfrag[2][4];
    #pragma unroll
    for (int half = 0; half < 2; ++half) {
        int c = wave * 32 + half * 16 + nidx;
        #pragma unroll
        for (int kk = 0; kk < 4; ++kk)
            bfrag[half][kk] = *(const short8*)(Wt + (size_t)c * DIM + kk * 32 + quad * 8);
    }

    __syncthreads();  // all hsrc reads complete before any aliased A write

    float4v acc0 = {0.f, 0.f, 0.f, 0.f};
    float4v acc1 = {0.f, 0.f, 0.f, 0.f};
    #pragma unroll
    for (int kk = 0; kk < 4; ++kk) {
        acc0 = __builtin_amdgcn_mfma_f32_16x16x32_bf16(afrag[kk], bfrag[0][kk], acc0, 0, 0, 0);
        acc1 = __builtin_amdgcn_mfma_f32_16x16x32_bf16(afrag[kk], bfrag[1][kk], acc1, 0, 0, 0);
    }

    #pragma unroll
    for (int r = 0; r < 4; ++r) {
        int row = row0 + quad * 4 + r;
        float d = dinv[row];
        float v0 = acc0[r] * d;
        float v1 = acc1[r] * d;
        size_t i0 = (size_t)row * DIM + wave * 32 + nidx;
        size_t i1 = i0 + 16;
        A[i0] = f32_to_bf16_bits(v0);
        A[i1] = f32_to_bf16_bits(v1);
        if (write_b) { B[i0] = v0; B[i1] = v1; }
    }
}

// ---------------- CSR gather: B[v] = A[v] + sum_in A[src]  (no atomics) ----------------
// One wave per node; half-waves process even/odd edges; lane covers 4 cols (8B bf16x4
// load); 2x unroll -> up to 4 edges in flight; __shfl_xor(32) combine; float4 store.
__global__ __launch_bounds__(256) void gather_csr(
    const int* __restrict__ row_ptr, const int* __restrict__ col_idx,
    const unsigned short* __restrict__ A, float* __restrict__ B) {
    const int wave = threadIdx.x >> 6;
    const int lane = threadIdx.x & 63;
    const int half = lane >> 5;        // 0: even edges + self, 1: odd edges
    const int lid  = lane & 31;
    const int node = blockIdx.x * 4 + wave;
    if (node >= N_NODES) return;
    const int lo = row_ptr[node];
    const int hi = row_ptr[node + 1];
    const int cbase = lid * 4;

    float a0 = 0.f, a1 = 0.f, a2 = 0.f, a3 = 0.f;
    if (half == 0) {
        uint2 su = *(const uint2*)(A + (size_t)node * DIM + cbase);
        a0 = bf16_lo(su.x); a1 = bf16_hi(su.x);
        a2 = bf16_lo(su.y); a3 = bf16_hi(su.y);
    }

    int e = lo + half;
    for (; e + 2 < hi; e += 4) {   // two edges per half-wave in flight
        int s0 = col_idx[e];
        int s1 = col_idx[e + 2];
        uint2 v0 = *(const uint2*)(A + (size_t)s0 * DIM + cbase);
        uint2 v1 = *(const uint2*)(A + (size_t)s1 * DIM + cbase);
        a0 += bf16_lo(v0.x); a1 += bf16_hi(v0.x);
        a2 += bf16_lo(v0.y); a3 += bf16_hi(v0.y);
        a0 += bf16_lo(v1.x); a1 += bf16_hi(v1.x);
        a2 += bf16_lo(v1.y); a3 += bf16_hi(v1.y);
    }
    if (e < hi) {
        int s0 = col_idx[e];
        uint2 v0 = *(const uint2*)(A + (size_t)s0 * DIM + cbase);
        a0 += bf16_lo(v0.x); a1 += bf16_hi(v0.x);
        a2 += bf16_lo(v0.y); a3 += bf16_hi(v0.y);
    }

    a0 += __shfl_xor(a0, 32);
    a1 += __shfl_xor(a1, 32);
    a2 += __shfl_xor(a2, 32);
    a3 += __shfl_xor(a3, 32);
    if (half == 0) {
        float4 st = {a0, a1, a2, a3};
        *(float4*)(B + (size_t)node * DIM + cbase) = st;
    }
}

// ---------------- scatter fallback (r7-proven) ----------------
__global__ __launch_bounds__(256) void scatter_edges(
    const int* __restrict__ src, const int* __restrict__ dst,
    const unsigned short* __restrict__ A, float* __restrict__ B) {
    int t = blockIdx.x * blockDim.x + threadIdx.x;
    int e = t >> 4;
    if (e >= N_EDGES) return;
    int f = (t & 15) * 8;
    int s = src[e], d = dst[e];
    short8 v = *(const short8*)(A + (size_t)s * DIM + f);
    float* bp = B + (size_t)d * DIM + f;
    #pragma unroll
    for (int j = 0; j < 8; ++j)
        atomicAdd(bp + j, bf16_bits_to_f32((unsigned short)v[j]));
}

__global__ __launch_bounds__(256) void make_dinv(const int* __restrict__ cnt,
                                                 float* __restrict__ dinv) {
    int v = blockIdx.x * blockDim.x + threadIdx.x;
    if (v < N_NODES) dinv[v] = rsqrtf((float)cnt[v] + 1.0f);
}

// ---------------- BN stats (oracle-verified r6) ----------------
__global__ __launch_bounds__(256) void bn_reduce(
    const float* __restrict__ B, const float* __restrict__ dinv,
    const float* __restrict__ bias,
    float* __restrict__ colsum, float* __restrict__ colsumsq) {
    int c = threadIdx.x & 127;
    int half = threadIdx.x >> 7;
    float bb = bias[c];
    float s = 0.f, s2 = 0.f;
    for (int row = blockIdx.x * 2 + half; row < N_NODES; row += gridDim.x * 2) {
        float v = dinv[row] * B[(size_t)row * DIM + c] + bb;
        s += v;
        s2 += v * v;
    }
    __shared__ float ls[128], ls2[128];
    if (half == 1) { ls[c] = s; ls2[c] = s2; }
    __syncthreads();
    if (half == 0) {
        atomicAdd(&colsum[c], s + ls[c]);
        atomicAdd(&colsumsq[c], s2 + ls2[c]);
    }
}

// ---------------- BN apply + ReLU; output dtype per mode on final layer ----------------
__global__ __launch_bounds__(256) void bn_apply(
    const float* __restrict__ B, const float* __restrict__ dinv,
    const float* __restrict__ prm, int l,
    const float* __restrict__ colsum, const float* __restrict__ colsumsq,
    const float* __restrict__ mode, int is_last,
    void* __restrict__ out) {
    int t = blockIdx.x * blockDim.x + threadIdx.x;
    if (t >= N_NODES * DIM) return;
    int row = t >> 7, c = t & 127;
    const float invN = 1.0f / N_NODES;
    float mu = colsum[c] * invN;
    float var = colsumsq[c] * invN - mu * mu;
    float istd = rsqrtf(var + BN_EPS);
    float vpre = dinv[row] * B[t] + prm[l * 128 + c];
    float vbn = prm[384 + l * 128 + c] * (vpre - mu) * istd + prm[768 + l * 128 + c];
    float r = fmaxf(vbn, 0.f);
    if (is_last && mode[0] > 0.5f)
        ((float*)out)[t] = r;
    else
        ((unsigned short*)out)[t] = f32_to_bf16_bits(r);
}

extern "C" void kernel_launch(void* const* d_in, const int* in_sizes, int n_in,
                              void* d_out, int out_size, void* d_ws, size_t ws_size,
                              hipStream_t stream) {
    const void* x  = d_in[0];
    const int*  ei = (const int*)d_in[1];
    const void* W  = d_in[2];
    const void* b  = d_in[3];
    const void* g  = d_in[4];
    const void* be = d_in[5];

    unsigned short* hA = (unsigned short*)d_out;  // bf16 msg / hidden buffer

    char* ws = (char*)d_ws;
    size_t off = 0;
    auto alloc = [&](size_t bytes) {
        char* p = ws + off;
        off = (off + bytes + 255) & ~(size_t)255;
        return p;
    };
    float* dinv     = (float*)alloc((size_t)N_NODES * 4);
    float* B        = (float*)alloc((size_t)N_NODES * DIM * 4);
    unsigned short* Wt = (unsigned short*)alloc((size_t)3 * DIM * DIM * 2);
    float* pf32     = (float*)alloc(3 * 3 * DIM * 4);
    float* colsum   = (float*)alloc(128 * 4);
    float* colsumsq = (float*)alloc(128 * 4);
    float* mode     = (float*)alloc(64 * 4);
    int*   cnt      = (int*)alloc((size_t)N_NODES * 4);
    int*   row_ptr  = (int*)alloc((size_t)(N_NODES + 1) * 4);
    int*   next     = (int*)alloc((size_t)N_NODES * 4);
    int*   bsum     = (int*)alloc(256 * 4);
    int*   col_idx  = (int*)alloc((size_t)N_EDGES * 4);
    const bool csr_ok = (ws_size >= off) || (ws_size == 0);

    const int* srcv = ei;            // edge_index[0]
    const int* dstv = ei + N_EDGES;  // edge_index[1]

    sniff<<<1, 256, 0, stream>>>((const unsigned short*)x, mode);
    convert_params<<<(3 * DIM * DIM + 3 * 3 * DIM + 255) / 256, 256, 0, stream>>>(
        W, b, g, be, mode, Wt, pf32);
    zero_int<<<(N_NODES + 255) / 256, 256, 0, stream>>>(cnt, N_NODES);
    hist_dst<<<(N_EDGES + 255) / 256, 256, 0, stream>>>(dstv, cnt);
    if (csr_ok) {
        block_sums<<<SCAN_BLOCKS, 256, 0, stream>>>(cnt, bsum);
        scan_bsums<<<1, 256, 0, stream>>>(bsum);
        scan_final<<<SCAN_BLOCKS, 256, 0, stream>>>(cnt, bsum, row_ptr, next, dinv);
        fill_csr<<<(N_EDGES + 255) / 256, 256, 0, stream>>>(srcv, dstv, next, col_idx);
    } else {
        make_dinv<<<(N_NODES + 255) / 256, 256, 0, stream>>>(cnt, dinv);
    }

    for (int l = 0; l < 3; ++l) {
        const void* hin = (l == 0) ? x : (const void*)hA;
        gemm_scale<<<N_NODES / 16, 256, 0, stream>>>(
            hin, (l == 0) ? 1 : 0, Wt + (size_t)l * DIM * DIM, dinv, mode, hA, B,
            csr_ok ? 0 : 1);
        if (csr_ok)
            gather_csr<<<(N_NODES + 3) / 4, 256, 0, stream>>>(row_ptr, col_idx, hA, B);
        else
            scatter_edges<<<(N_EDGES * 16) / 256, 256, 0, stream>>>(srcv, dstv, hA, B);
        zero_buf<<<1, 256, 0, stream>>>(colsum, 256);
        bn_reduce<<<256, 256, 0, stream>>>(B, dinv, pf32 + l * 128, colsum, colsumsq);
        bn_apply<<<(N_NODES * DIM) / 256, 256, 0, stream>>>(
            B, dinv, pf32, l, colsum, colsumsq, mode, (l == 2) ? 1 : 0, d_out);
    }
}